// Round 1
// baseline (1042.617 us; speedup 1.0000x reference)
//
#include <hip/hip_runtime.h>
#include <hip/hip_bf16.h>
#include <math.h>

#define N_NODES 16384
#define E_EDGES 65536
#define ET (E_EDGES + N_NODES)   /* 81920 edges incl self loops */
#define IN_DIM 1536
#define HID 1024

typedef __attribute__((ext_vector_type(8))) short bf16x8;
typedef __attribute__((ext_vector_type(4))) float f32x4;

__device__ __forceinline__ unsigned short f2b(float f) {
  unsigned int u = __float_as_uint(f);
  u = (u + 0x7FFFu + ((u >> 16) & 1u)) >> 16;
  return (unsigned short)u;
}

__device__ __forceinline__ void gload_lds16(const void* g, void* l) {
  __builtin_amdgcn_global_load_lds((const __attribute__((address_space(1))) void*)g,
                                   (__attribute__((address_space(3))) void*)l, 16, 0, 0);
}

__device__ __forceinline__ float gelu_exact(float y) {
  return 0.5f * y * (1.0f + erff(y * 0.70710678118654752f));
}

// ---------------------------------------------------------------------------
// fp32 -> bf16 convert (vectorized)
__global__ void conv_bf16_kernel(const float* __restrict__ in, unsigned short* __restrict__ out, int n4) {
  int i = blockIdx.x * 256 + threadIdx.x;
  if (i < n4) {
    float4 v = ((const float4*)in)[i];
    ushort4 o;
    o.x = f2b(v.x); o.y = f2b(v.y); o.z = f2b(v.z); o.w = f2b(v.w);
    ((ushort4*)out)[i] = o;
  }
}

// transpose fp32 [K][N] -> bf16 [N][K]
__global__ void transpose_conv_kernel(const float* __restrict__ in, unsigned short* __restrict__ out,
                                      int K, int N) {
  __shared__ float tile[32][33];
  int bx = blockIdx.x * 32;  // n base
  int by = blockIdx.y * 32;  // k base
  int tx = threadIdx.x, ty = threadIdx.y;
  #pragma unroll
  for (int i = 0; i < 32; i += 8)
    tile[ty + i][tx] = in[(size_t)(by + ty + i) * N + bx + tx];
  __syncthreads();
  #pragma unroll
  for (int i = 0; i < 32; i += 8)
    out[(size_t)(bx + ty + i) * K + by + tx] = f2b(tile[tx][ty + i]);
}

// ---------------------------------------------------------------------------
// bf16 MFMA GEMM: C[M,N] = A[M,K](bf16) * Bt[N,K](bf16)^T + bias
// 128x128 tile, BK=32, 4 waves (2x2), each wave 64x64 via 4x4 16x16x32 MFMAs
// ACT: 0 none, 1 silu.  WB: also write bf16 copy of C.
template <int ACT, int WB>
__global__ __launch_bounds__(256)
void gemm_bf16_kernel(const unsigned short* __restrict__ A, const unsigned short* __restrict__ Bt,
                      const float* __restrict__ bias, float* __restrict__ C,
                      unsigned short* __restrict__ Cb, int M, int N, int K) {
  __shared__ unsigned short As[128 * 32];
  __shared__ unsigned short Bs[128 * 32];
  const int t = threadIdx.x;
  const int l = t & 63;
  const int w = t >> 6;
  const int wr = w >> 1, wc = w & 1;
  const int bm = blockIdx.y * 128;
  const int bn = blockIdx.x * 128;

  f32x4 acc[4][4];
  #pragma unroll
  for (int m = 0; m < 4; m++)
    #pragma unroll
    for (int n = 0; n < 4; n++) acc[m][n] = (f32x4){0.f, 0.f, 0.f, 0.f};

  const int srow = t >> 2;            // 0..63
  const int scol = (t & 3) * 8;       // 0,8,16,24
  const unsigned short* Ag0 = A + (size_t)(bm + srow) * K + scol;
  const unsigned short* Ag1 = A + (size_t)(bm + 64 + srow) * K + scol;
  const unsigned short* Bg0 = Bt + (size_t)(bn + srow) * K + scol;
  const unsigned short* Bg1 = Bt + (size_t)(bn + 64 + srow) * K + scol;

  const int ar = wr * 64 + (l & 15);
  const int br = wc * 64 + (l & 15);
  const int kk = (l >> 4) * 8;

  for (int k0 = 0; k0 < K; k0 += 32) {
    gload_lds16(Ag0 + k0, &As[t * 8]);
    gload_lds16(Ag1 + k0, &As[2048 + t * 8]);
    gload_lds16(Bg0 + k0, &Bs[t * 8]);
    gload_lds16(Bg1 + k0, &Bs[2048 + t * 8]);
    __syncthreads();
    bf16x8 af[4], bfr[4];
    #pragma unroll
    for (int m = 0; m < 4; m++) af[m] = *(const bf16x8*)&As[(ar + m * 16) * 32 + kk];
    #pragma unroll
    for (int n = 0; n < 4; n++) bfr[n] = *(const bf16x8*)&Bs[(br + n * 16) * 32 + kk];
    #pragma unroll
    for (int m = 0; m < 4; m++)
      #pragma unroll
      for (int n = 0; n < 4; n++)
        acc[m][n] = __builtin_amdgcn_mfma_f32_16x16x32_bf16(af[m], bfr[n], acc[m][n], 0, 0, 0);
    __syncthreads();
  }

  const int crow0 = bm + wr * 64 + (l >> 4) * 4;
  const int ccol0 = bn + wc * 64 + (l & 15);
  #pragma unroll
  for (int m = 0; m < 4; m++) {
    #pragma unroll
    for (int n = 0; n < 4; n++) {
      int col = ccol0 + n * 16;
      float bv = bias[col];
      #pragma unroll
      for (int v = 0; v < 4; v++) {
        int row = crow0 + m * 16 + v;
        float x = acc[m][n][v] + bv;
        if (ACT == 1) x = x / (1.0f + expf(-x));   // silu
        C[(size_t)row * N + col] = x;
        if (WB) Cb[(size_t)row * N + col] = f2b(x);
      }
    }
  }
}

// ---------------------------------------------------------------------------
// layernorm + exact gelu (+ optional residual into h); writes h fp32 and bf16
template <int RES>
__global__ __launch_bounds__(256)
void ln_gelu_kernel(const float* __restrict__ c, const float* __restrict__ g,
                    const float* __restrict__ b, float* __restrict__ h,
                    unsigned short* __restrict__ hb) {
  int row = blockIdx.x;
  int t = threadIdx.x;
  const float* cr = c + (size_t)row * HID;
  float v[4];
  float s = 0.f, q = 0.f;
  #pragma unroll
  for (int j = 0; j < 4; j++) {
    v[j] = cr[t + 256 * j];
    s += v[j];
    q += v[j] * v[j];
  }
  #pragma unroll
  for (int off = 32; off; off >>= 1) {
    s += __shfl_xor(s, off);
    q += __shfl_xor(q, off);
  }
  __shared__ float rs[4], rq[4];
  int wv = t >> 6, l = t & 63;
  if (l == 0) { rs[wv] = s; rq[wv] = q; }
  __syncthreads();
  s = rs[0] + rs[1] + rs[2] + rs[3];
  q = rq[0] + rq[1] + rq[2] + rq[3];
  float mu = s * (1.0f / HID);
  float var = q * (1.0f / HID) - mu * mu;
  float rstd = rsqrtf(var + 1e-5f);
  float* hr = h + (size_t)row * HID;
  unsigned short* hbr = hb + (size_t)row * HID;
  #pragma unroll
  for (int j = 0; j < 4; j++) {
    int ci = t + 256 * j;
    float y = (v[j] - mu) * rstd * g[ci] + b[ci];
    float z = gelu_exact(y);
    float o = RES ? (hr[ci] + z) : z;
    hr[ci] = o;
    hbr[ci] = f2b(o);
  }
}

// ---------------------------------------------------------------------------
// edge list build (+ self loops) and dst-degree histogram
__global__ void build_edges_kernel(const int* __restrict__ ei, int* __restrict__ srcA,
                                   int* __restrict__ dstA, int* __restrict__ deg) {
  int i = blockIdx.x * 256 + threadIdx.x;
  if (i >= ET) return;
  int s, d;
  if (i < E_EDGES) { s = ei[i]; d = ei[E_EDGES + i]; }
  else             { s = i - E_EDGES; d = s; }
  srcA[i] = s;
  dstA[i] = d;
  atomicAdd(&deg[d], 1);
}

// exclusive scan of 16384 degrees, single block of 1024 threads
__global__ __launch_bounds__(1024)
void scan16k_kernel(const int* __restrict__ deg, int* __restrict__ rowstart) {
  __shared__ int s[1024];
  int t = threadIdx.x;
  int local[16];
  int sum = 0;
  #pragma unroll
  for (int i = 0; i < 16; i++) { local[i] = deg[t * 16 + i]; sum += local[i]; }
  s[t] = sum;
  __syncthreads();
  for (int off = 1; off < 1024; off <<= 1) {
    int v = (t >= off) ? s[t - off] : 0;
    __syncthreads();
    s[t] += v;
    __syncthreads();
  }
  int run = s[t] - sum;
  #pragma unroll
  for (int i = 0; i < 16; i++) { rowstart[t * 16 + i] = run; run += local[i]; }
  if (t == 1023) rowstart[16384] = run;
}

__global__ void scatter_edges_kernel(const int* __restrict__ dstA, const int* __restrict__ rowstart,
                                     int* __restrict__ cursor, int* __restrict__ eids) {
  int i = blockIdx.x * 256 + threadIdx.x;
  if (i >= ET) return;
  int d = dstA[i];
  int pos = atomicAdd(&cursor[d], 1);
  eids[rowstart[d] + pos] = i;
}

// ---------------------------------------------------------------------------
// per-edge attention logits: logit[e][h] = sum_c lrelu(xl[s]+xr[d]) * att[h]
__global__ __launch_bounds__(256)
void edge_logits_kernel(const float* __restrict__ xl, const float* __restrict__ xr,
                        const float* __restrict__ att, const int* __restrict__ srcA,
                        const int* __restrict__ dstA, float* __restrict__ logits) {
  int e = blockIdx.x * 4 + (threadIdx.x >> 6);
  int l = threadIdx.x & 63;
  int s = srcA[e], d = dstA[e];
  const float* xls = xl + (size_t)s * HID;
  const float* xrd = xr + (size_t)d * HID;
  #pragma unroll
  for (int hh = 0; hh < 8; hh++) {
    int c = hh * 128 + l;
    float a1 = xls[c] + xrd[c];
    float a2 = xls[c + 64] + xrd[c + 64];
    a1 = a1 > 0.f ? a1 : 0.2f * a1;
    a2 = a2 > 0.f ? a2 : 0.2f * a2;
    float p = a1 * att[c] + a2 * att[c + 64];
    #pragma unroll
    for (int off = 32; off; off >>= 1) p += __shfl_xor(p, off);
    if (l == 0) logits[(size_t)e * 8 + hh] = p;
  }
}

// per-dst softmax + aggregate: out[n] = sum_e alpha[e]*xl[src_e] + bo
__global__ __launch_bounds__(256)
void gat_aggregate_kernel(const float* __restrict__ xl, const float* __restrict__ logits,
                          const int* __restrict__ eids, const int* __restrict__ rowstart,
                          const int* __restrict__ srcA, const float* __restrict__ bo,
                          float* __restrict__ out) {
  int nid = blockIdx.x;
  int beg = rowstart[nid], end = rowstart[nid + 1];
  int t = threadIdx.x;
  __shared__ float mh[8], dh[8];
  if (t < 8) {
    float m = -1e30f;
    for (int i = beg; i < end; i++) {
      float lg = logits[(size_t)eids[i] * 8 + t];
      m = fmaxf(m, lg);
    }
    float den = 0.f;
    for (int i = beg; i < end; i++) den += expf(logits[(size_t)eids[i] * 8 + t] - m);
    mh[t] = m;
    dh[t] = den;
  }
  __syncthreads();
  #pragma unroll
  for (int j = 0; j < 4; j++) {
    int c = t + 256 * j;
    int hh = c >> 7;
    float m = mh[hh];
    float inv = 1.0f / dh[hh];
    float acc = 0.f;
    for (int i = beg; i < end; i++) {
      int eid = eids[i];
      float wgt = expf(logits[(size_t)eid * 8 + hh] - m) * inv;
      acc += wgt * xl[(size_t)srcA[eid] * HID + c];
    }
    out[(size_t)nid * HID + c] = acc + bo[c];
  }
}

// final scorer dot: scores[n] = dot(s2[n][0:128], Ws3) + bs3
__global__ __launch_bounds__(256)
void score_kernel(const float* __restrict__ s2, const float* __restrict__ Ws3,
                  const float* __restrict__ bs3, float* __restrict__ out) {
  int nid = blockIdx.x * 4 + (threadIdx.x >> 6);
  int l = threadIdx.x & 63;
  const float* r = s2 + (size_t)nid * 128;
  float a = r[l] * Ws3[l] + r[l + 64] * Ws3[l + 64];
  #pragma unroll
  for (int off = 32; off; off >>= 1) a += __shfl_xor(a, off);
  if (l == 0) out[nid] = a + bs3[0];
}

// ---------------------------------------------------------------------------
extern "C" void kernel_launch(void* const* d_in, const int* in_sizes, int n_in,
                              void* d_out, int out_size, void* d_ws, size_t ws_size,
                              hipStream_t stream) {
  const float* x    = (const float*)d_in[0];
  const int*   ei   = (const int*)  d_in[1];
  const float* W_in = (const float*)d_in[2];
  const float* b_in = (const float*)d_in[3];
  const float* ln1g = (const float*)d_in[4];
  const float* ln1b = (const float*)d_in[5];
  const float* g1Wl = (const float*)d_in[6];
  const float* g1bl = (const float*)d_in[7];
  const float* g1Wr = (const float*)d_in[8];
  const float* g1br = (const float*)d_in[9];
  const float* g1att= (const float*)d_in[10];
  const float* g1bo = (const float*)d_in[11];
  const float* ln2g = (const float*)d_in[12];
  const float* ln2b = (const float*)d_in[13];
  const float* g2Wl = (const float*)d_in[14];
  const float* g2bl = (const float*)d_in[15];
  const float* g2Wr = (const float*)d_in[16];
  const float* g2br = (const float*)d_in[17];
  const float* g2att= (const float*)d_in[18];
  const float* g2bo = (const float*)d_in[19];
  const float* ln3g = (const float*)d_in[20];
  const float* ln3b = (const float*)d_in[21];
  const float* Ws1  = (const float*)d_in[22];
  const float* bs1  = (const float*)d_in[23];
  const float* Ws2  = (const float*)d_in[24];
  const float* bs2  = (const float*)d_in[25];
  const float* Ws3  = (const float*)d_in[26];
  const float* bs3  = (const float*)d_in[27];

  float* scores = (float*)d_out;
  float* h      = (float*)d_out + N_NODES;  // [N][1024] fp32, second output

  char* wsp = (char*)d_ws;
  size_t off = 0;
  auto alloc = [&](size_t bytes) -> char* {
    char* p = wsp + off;
    off += (bytes + 255) & ~(size_t)255;
    return p;
  };
  unsigned short* xb    = (unsigned short*)alloc((size_t)N_NODES * IN_DIM * 2);
  unsigned short* WinT  = (unsigned short*)alloc((size_t)HID * IN_DIM * 2);
  unsigned short* g1WlT = (unsigned short*)alloc((size_t)HID * HID * 2);
  unsigned short* g1WrT = (unsigned short*)alloc((size_t)HID * HID * 2);
  unsigned short* g2WlT = (unsigned short*)alloc((size_t)HID * HID * 2);
  unsigned short* g2WrT = (unsigned short*)alloc((size_t)HID * HID * 2);
  unsigned short* Ws1T  = (unsigned short*)alloc((size_t)512 * HID * 2);
  unsigned short* Ws2T  = (unsigned short*)alloc((size_t)128 * 512 * 2);
  unsigned short* hb    = (unsigned short*)alloc((size_t)N_NODES * HID * 2);
  unsigned short* s1b   = (unsigned short*)alloc((size_t)N_NODES * 512 * 2);
  float* C      = (float*)alloc((size_t)N_NODES * HID * 4);
  float* xlb    = (float*)alloc((size_t)N_NODES * HID * 4);
  float* xrb    = (float*)alloc((size_t)N_NODES * HID * 4);
  float* logits = (float*)alloc((size_t)ET * 8 * 4);
  int* srcA     = (int*)alloc((size_t)ET * 4);
  int* dstA     = (int*)alloc((size_t)ET * 4);
  int* deg      = (int*)alloc(65536);
  int* cursor   = (int*)alloc(65536);
  int* rowstart = (int*)alloc(65544);
  int* eids     = (int*)alloc((size_t)ET * 4);

  // --- weight/input conversions ---
  conv_bf16_kernel<<<(N_NODES * IN_DIM / 4 + 255) / 256, 256, 0, stream>>>(x, xb, N_NODES * IN_DIM / 4);
  dim3 tb(32, 8);
  transpose_conv_kernel<<<dim3(HID / 32, IN_DIM / 32), tb, 0, stream>>>(W_in, WinT, IN_DIM, HID);
  transpose_conv_kernel<<<dim3(HID / 32, HID / 32), tb, 0, stream>>>(g1Wl, g1WlT, HID, HID);
  transpose_conv_kernel<<<dim3(HID / 32, HID / 32), tb, 0, stream>>>(g1Wr, g1WrT, HID, HID);
  transpose_conv_kernel<<<dim3(HID / 32, HID / 32), tb, 0, stream>>>(g2Wl, g2WlT, HID, HID);
  transpose_conv_kernel<<<dim3(HID / 32, HID / 32), tb, 0, stream>>>(g2Wr, g2WrT, HID, HID);
  transpose_conv_kernel<<<dim3(512 / 32, HID / 32), tb, 0, stream>>>(Ws1, Ws1T, HID, 512);
  transpose_conv_kernel<<<dim3(128 / 32, 512 / 32), tb, 0, stream>>>(Ws2, Ws2T, 512, 128);

  // --- CSR build (shared by both GAT layers) ---
  hipMemsetAsync(deg, 0, 131072, stream);  // deg + cursor (contiguous)
  build_edges_kernel<<<ET / 256, 256, 0, stream>>>(ei, srcA, dstA, deg);
  scan16k_kernel<<<1, 1024, 0, stream>>>(deg, rowstart);
  scatter_edges_kernel<<<ET / 256, 256, 0, stream>>>(dstA, rowstart, cursor, eids);

  // --- input projection + LN1 + gelu ---
  gemm_bf16_kernel<0, 0><<<dim3(HID / 128, N_NODES / 128), 256, 0, stream>>>(
      xb, WinT, b_in, C, nullptr, N_NODES, HID, IN_DIM);
  ln_gelu_kernel<0><<<N_NODES, 256, 0, stream>>>(C, ln1g, ln1b, h, hb);

  // --- GAT layer 1 ---
  gemm_bf16_kernel<0, 0><<<dim3(HID / 128, N_NODES / 128), 256, 0, stream>>>(
      hb, g1WlT, g1bl, xlb, nullptr, N_NODES, HID, HID);
  gemm_bf16_kernel<0, 0><<<dim3(HID / 128, N_NODES / 128), 256, 0, stream>>>(
      hb, g1WrT, g1br, xrb, nullptr, N_NODES, HID, HID);
  edge_logits_kernel<<<ET / 4, 256, 0, stream>>>(xlb, xrb, g1att, srcA, dstA, logits);
  gat_aggregate_kernel<<<N_NODES, 256, 0, stream>>>(xlb, logits, eids, rowstart, srcA, g1bo, C);
  ln_gelu_kernel<1><<<N_NODES, 256, 0, stream>>>(C, ln2g, ln2b, h, hb);

  // --- GAT layer 2 ---
  gemm_bf16_kernel<0, 0><<<dim3(HID / 128, N_NODES / 128), 256, 0, stream>>>(
      hb, g2WlT, g2bl, xlb, nullptr, N_NODES, HID, HID);
  gemm_bf16_kernel<0, 0><<<dim3(HID / 128, N_NODES / 128), 256, 0, stream>>>(
      hb, g2WrT, g2br, xrb, nullptr, N_NODES, HID, HID);
  edge_logits_kernel<<<ET / 4, 256, 0, stream>>>(xlb, xrb, g2att, srcA, dstA, logits);
  gat_aggregate_kernel<<<N_NODES, 256, 0, stream>>>(xlb, logits, eids, rowstart, srcA, g2bo, C);
  ln_gelu_kernel<1><<<N_NODES, 256, 0, stream>>>(C, ln3g, ln3b, h, hb);

  // --- scorer MLP ---
  gemm_bf16_kernel<1, 1><<<dim3(512 / 128, N_NODES / 128), 256, 0, stream>>>(
      hb, Ws1T, bs1, C, s1b, N_NODES, 512, HID);
  gemm_bf16_kernel<1, 0><<<dim3(128 / 128, N_NODES / 128), 256, 0, stream>>>(
      s1b, Ws2T, bs2, C, nullptr, N_NODES, 128, 512);
  score_kernel<<<N_NODES / 4, 256, 0, stream>>>(C, Ws3, bs3, scores);
}

// Round 2
// 728.674 us; speedup vs baseline: 1.4308x; 1.4308x over previous
//
#include <hip/hip_runtime.h>
#include <hip/hip_bf16.h>
#include <math.h>

#define N_NODES 16384
#define E_EDGES 65536
#define ET (E_EDGES + N_NODES)   /* 81920 edges incl self loops */
#define IN_DIM 1536
#define HID 1024

typedef __attribute__((ext_vector_type(8))) short bf16x8;
typedef __attribute__((ext_vector_type(4))) float f32x4;

__device__ __forceinline__ unsigned short f2b(float f) {
  unsigned int u = __float_as_uint(f);
  u = (u + 0x7FFFu + ((u >> 16) & 1u)) >> 16;
  return (unsigned short)u;
}

__device__ __forceinline__ float b2f(unsigned short u) {
  return __uint_as_float((unsigned int)u << 16);
}

__device__ __forceinline__ void gload_lds16(const void* g, void* l) {
  __builtin_amdgcn_global_load_lds((const __attribute__((address_space(1))) void*)g,
                                   (__attribute__((address_space(3))) void*)l, 16, 0, 0);
}

__device__ __forceinline__ float gelu_exact(float y) {
  return 0.5f * y * (1.0f + erff(y * 0.70710678118654752f));
}

// ---------------------------------------------------------------------------
// fp32 -> bf16 convert (vectorized)
__global__ void conv_bf16_kernel(const float* __restrict__ in, unsigned short* __restrict__ out, int n4) {
  int i = blockIdx.x * 256 + threadIdx.x;
  if (i < n4) {
    float4 v = ((const float4*)in)[i];
    ushort4 o;
    o.x = f2b(v.x); o.y = f2b(v.y); o.z = f2b(v.z); o.w = f2b(v.w);
    ((ushort4*)out)[i] = o;
  }
}

// transpose fp32 [K][N] -> bf16 [N][K]
__global__ void transpose_conv_kernel(const float* __restrict__ in, unsigned short* __restrict__ out,
                                      int K, int N) {
  __shared__ float tile[32][33];
  int bx = blockIdx.x * 32;  // n base
  int by = blockIdx.y * 32;  // k base
  int tx = threadIdx.x, ty = threadIdx.y;
  #pragma unroll
  for (int i = 0; i < 32; i += 8)
    tile[ty + i][tx] = in[(size_t)(by + ty + i) * N + bx + tx];
  __syncthreads();
  #pragma unroll
  for (int i = 0; i < 32; i += 8)
    out[(size_t)(bx + ty + i) * K + by + tx] = f2b(tile[tx][ty + i]);
}

// ---------------------------------------------------------------------------
// bf16 MFMA GEMM: C[M,N] = A[M,K](bf16) * Bt[N,K](bf16)^T + bias
// 128x128 tile, BK=32, 4 waves (2x2), each wave 64x64 via 4x4 16x16x32 MFMAs
// ACT: 0 none, 1 silu.  WB: 0 fp32 only, 1 fp32+bf16, 2 bf16 only.
template <int ACT, int WB>
__global__ __launch_bounds__(256)
void gemm_bf16_kernel(const unsigned short* __restrict__ A, const unsigned short* __restrict__ Bt,
                      const float* __restrict__ bias, float* __restrict__ C,
                      unsigned short* __restrict__ Cb, int M, int N, int K) {
  __shared__ unsigned short As[128 * 32];
  __shared__ unsigned short Bs[128 * 32];
  const int t = threadIdx.x;
  const int l = t & 63;
  const int w = t >> 6;
  const int wr = w >> 1, wc = w & 1;
  const int bm = blockIdx.y * 128;
  const int bn = blockIdx.x * 128;

  f32x4 acc[4][4];
  #pragma unroll
  for (int m = 0; m < 4; m++)
    #pragma unroll
    for (int n = 0; n < 4; n++) acc[m][n] = (f32x4){0.f, 0.f, 0.f, 0.f};

  const int srow = t >> 2;            // 0..63
  const int scol = (t & 3) * 8;       // 0,8,16,24
  const unsigned short* Ag0 = A + (size_t)(bm + srow) * K + scol;
  const unsigned short* Ag1 = A + (size_t)(bm + 64 + srow) * K + scol;
  const unsigned short* Bg0 = Bt + (size_t)(bn + srow) * K + scol;
  const unsigned short* Bg1 = Bt + (size_t)(bn + 64 + srow) * K + scol;

  const int ar = wr * 64 + (l & 15);
  const int br = wc * 64 + (l & 15);
  const int kk = (l >> 4) * 8;

  for (int k0 = 0; k0 < K; k0 += 32) {
    gload_lds16(Ag0 + k0, &As[t * 8]);
    gload_lds16(Ag1 + k0, &As[2048 + t * 8]);
    gload_lds16(Bg0 + k0, &Bs[t * 8]);
    gload_lds16(Bg1 + k0, &Bs[2048 + t * 8]);
    __syncthreads();
    bf16x8 af[4], bfr[4];
    #pragma unroll
    for (int m = 0; m < 4; m++) af[m] = *(const bf16x8*)&As[(ar + m * 16) * 32 + kk];
    #pragma unroll
    for (int n = 0; n < 4; n++) bfr[n] = *(const bf16x8*)&Bs[(br + n * 16) * 32 + kk];
    #pragma unroll
    for (int m = 0; m < 4; m++)
      #pragma unroll
      for (int n = 0; n < 4; n++)
        acc[m][n] = __builtin_amdgcn_mfma_f32_16x16x32_bf16(af[m], bfr[n], acc[m][n], 0, 0, 0);
    __syncthreads();
  }

  const int crow0 = bm + wr * 64 + (l >> 4) * 4;
  const int ccol0 = bn + wc * 64 + (l & 15);
  #pragma unroll
  for (int m = 0; m < 4; m++) {
    #pragma unroll
    for (int n = 0; n < 4; n++) {
      int col = ccol0 + n * 16;
      float bv = bias[col];
      #pragma unroll
      for (int v = 0; v < 4; v++) {
        int row = crow0 + m * 16 + v;
        float x = acc[m][n][v] + bv;
        if (ACT == 1) x = x / (1.0f + expf(-x));   // silu
        if (WB != 2) C[(size_t)row * N + col] = x;
        if (WB != 0) Cb[(size_t)row * N + col] = f2b(x);
      }
    }
  }
}

// ---------------------------------------------------------------------------
// layernorm + exact gelu (+ optional residual into h); writes h fp32 and bf16
template <int RES>
__global__ __launch_bounds__(256)
void ln_gelu_kernel(const float* __restrict__ c, const float* __restrict__ g,
                    const float* __restrict__ b, float* __restrict__ h,
                    unsigned short* __restrict__ hb) {
  int row = blockIdx.x;
  int t = threadIdx.x;
  const float* cr = c + (size_t)row * HID;
  float v[4];
  float s = 0.f, q = 0.f;
  #pragma unroll
  for (int j = 0; j < 4; j++) {
    v[j] = cr[t + 256 * j];
    s += v[j];
    q += v[j] * v[j];
  }
  #pragma unroll
  for (int off = 32; off; off >>= 1) {
    s += __shfl_xor(s, off);
    q += __shfl_xor(q, off);
  }
  __shared__ float rs[4], rq[4];
  int wv = t >> 6, l = t & 63;
  if (l == 0) { rs[wv] = s; rq[wv] = q; }
  __syncthreads();
  s = rs[0] + rs[1] + rs[2] + rs[3];
  q = rq[0] + rq[1] + rq[2] + rq[3];
  float mu = s * (1.0f / HID);
  float var = q * (1.0f / HID) - mu * mu;
  float rstd = rsqrtf(var + 1e-5f);
  float* hr = h + (size_t)row * HID;
  unsigned short* hbr = hb + (size_t)row * HID;
  #pragma unroll
  for (int j = 0; j < 4; j++) {
    int ci = t + 256 * j;
    float y = (v[j] - mu) * rstd * g[ci] + b[ci];
    float z = gelu_exact(y);
    float o = RES ? (hr[ci] + z) : z;
    hr[ci] = o;
    hbr[ci] = f2b(o);
  }
}

// ---------------------------------------------------------------------------
// edge list build (+ self loops) and dst-degree histogram
__global__ void build_edges_kernel(const int* __restrict__ ei, int* __restrict__ srcA,
                                   int* __restrict__ dstA, int* __restrict__ deg) {
  int i = blockIdx.x * 256 + threadIdx.x;
  if (i >= ET) return;
  int s, d;
  if (i < E_EDGES) { s = ei[i]; d = ei[E_EDGES + i]; }
  else             { s = i - E_EDGES; d = s; }
  srcA[i] = s;
  dstA[i] = d;
  atomicAdd(&deg[d], 1);
}

// exclusive scan of 16384 degrees, single block of 1024 threads
__global__ __launch_bounds__(1024)
void scan16k_kernel(const int* __restrict__ deg, int* __restrict__ rowstart) {
  __shared__ int s[1024];
  int t = threadIdx.x;
  int local[16];
  int sum = 0;
  #pragma unroll
  for (int i = 0; i < 16; i++) { local[i] = deg[t * 16 + i]; sum += local[i]; }
  s[t] = sum;
  __syncthreads();
  for (int off = 1; off < 1024; off <<= 1) {
    int v = (t >= off) ? s[t - off] : 0;
    __syncthreads();
    s[t] += v;
    __syncthreads();
  }
  int run = s[t] - sum;
  #pragma unroll
  for (int i = 0; i < 16; i++) { rowstart[t * 16 + i] = run; run += local[i]; }
  if (t == 1023) rowstart[16384] = run;
}

// scatter edges into CSR slots; store src and dst per CSR position
__global__ void scatter_edges_kernel(const int* __restrict__ srcA, const int* __restrict__ dstA,
                                     const int* __restrict__ rowstart, int* __restrict__ cursor,
                                     int* __restrict__ src_csr, int* __restrict__ dst_csr) {
  int i = blockIdx.x * 256 + threadIdx.x;
  if (i >= ET) return;
  int d = dstA[i];
  int pos = atomicAdd(&cursor[d], 1);
  int p = rowstart[d] + pos;
  src_csr[p] = srcA[i];
  dst_csr[p] = d;
}

// ---------------------------------------------------------------------------
// per-edge attention logits over CSR order (consecutive waves share dst row).
// One wave per CSR slot; lane l covers channels [16l, 16l+16).
__global__ __launch_bounds__(256)
void edge_logits_kernel(const unsigned short* __restrict__ xl, const unsigned short* __restrict__ xr,
                        const float* __restrict__ att, const int* __restrict__ src_csr,
                        const int* __restrict__ dst_csr, float* __restrict__ logits) {
  int e = blockIdx.x * 4 + (threadIdx.x >> 6);
  int l = threadIdx.x & 63;
  int s = src_csr[e], d = dst_csr[e];
  const unsigned short* xls = xl + (size_t)s * HID + l * 16;
  const unsigned short* xrd = xr + (size_t)d * HID + l * 16;
  bf16x8 a0 = *(const bf16x8*)xls;
  bf16x8 a1 = *(const bf16x8*)(xls + 8);
  bf16x8 b0 = *(const bf16x8*)xrd;
  bf16x8 b1 = *(const bf16x8*)(xrd + 8);
  const float* ac = att + l * 16;
  float p = 0.f;
  #pragma unroll
  for (int j = 0; j < 8; j++) {
    float u = b2f((unsigned short)a0[j]) + b2f((unsigned short)b0[j]);
    float v = b2f((unsigned short)a1[j]) + b2f((unsigned short)b1[j]);
    u = u > 0.f ? u : 0.2f * u;
    v = v > 0.f ? v : 0.2f * v;
    p += u * ac[j] + v * ac[j + 8];
  }
  p += __shfl_xor(p, 1);
  p += __shfl_xor(p, 2);
  p += __shfl_xor(p, 4);
  if ((l & 7) == 0) logits[(size_t)e * 8 + (l >> 3)] = p;
}

// per-(node,head) softmax over CSR-contiguous logits -> alpha
__global__ __launch_bounds__(256)
void alpha_kernel(const float* __restrict__ logits, const int* __restrict__ rowstart,
                  float* __restrict__ alpha) {
  int gid = blockIdx.x * 256 + threadIdx.x;
  if (gid >= N_NODES * 8) return;
  int nid = gid >> 3, hh = gid & 7;
  int beg = rowstart[nid], end = rowstart[nid + 1];
  float m = -1e30f;
  for (int i = beg; i < end; i++) m = fmaxf(m, logits[(size_t)i * 8 + hh]);
  float den = 0.f;
  for (int i = beg; i < end; i++) den += expf(logits[(size_t)i * 8 + hh] - m);
  float inv = 1.0f / den;
  for (int i = beg; i < end; i++) alpha[(size_t)i * 8 + hh] = expf(logits[(size_t)i * 8 + hh] - m) * inv;
}

// per-dst aggregate: out[n] = sum_e alpha[e]*xl[src_e] + bo   (bf16 gathers)
__global__ __launch_bounds__(256)
void gat_aggregate_kernel(const unsigned short* __restrict__ xl, const float* __restrict__ alpha,
                          const int* __restrict__ src_csr, const int* __restrict__ rowstart,
                          const float* __restrict__ bo, float* __restrict__ out) {
  int nid = blockIdx.x;
  int beg = rowstart[nid], end = rowstart[nid + 1];
  int t = threadIdx.x;
  int c0 = t * 4;
  int hh = t >> 5;          // c0>>7
  float acc0 = 0.f, acc1 = 0.f, acc2 = 0.f, acc3 = 0.f;
  for (int i = beg; i < end; i++) {
    float a = alpha[(size_t)i * 8 + hh];
    int s = src_csr[i];
    ushort4 v = *(const ushort4*)(xl + (size_t)s * HID + c0);
    acc0 += a * b2f(v.x);
    acc1 += a * b2f(v.y);
    acc2 += a * b2f(v.z);
    acc3 += a * b2f(v.w);
  }
  const float4 bv = *(const float4*)(bo + c0);
  float4 o;
  o.x = acc0 + bv.x; o.y = acc1 + bv.y; o.z = acc2 + bv.z; o.w = acc3 + bv.w;
  *(float4*)(out + (size_t)nid * HID + c0) = o;
}

// final scorer dot: scores[n] = dot(s2[n][0:128], Ws3) + bs3
__global__ __launch_bounds__(256)
void score_kernel(const float* __restrict__ s2, const float* __restrict__ Ws3,
                  const float* __restrict__ bs3, float* __restrict__ out) {
  int nid = blockIdx.x * 4 + (threadIdx.x >> 6);
  int l = threadIdx.x & 63;
  const float* r = s2 + (size_t)nid * 128;
  float a = r[l] * Ws3[l] + r[l + 64] * Ws3[l + 64];
  #pragma unroll
  for (int off = 32; off; off >>= 1) a += __shfl_xor(a, off);
  if (l == 0) out[nid] = a + bs3[0];
}

// ---------------------------------------------------------------------------
extern "C" void kernel_launch(void* const* d_in, const int* in_sizes, int n_in,
                              void* d_out, int out_size, void* d_ws, size_t ws_size,
                              hipStream_t stream) {
  const float* x    = (const float*)d_in[0];
  const int*   ei   = (const int*)  d_in[1];
  const float* W_in = (const float*)d_in[2];
  const float* b_in = (const float*)d_in[3];
  const float* ln1g = (const float*)d_in[4];
  const float* ln1b = (const float*)d_in[5];
  const float* g1Wl = (const float*)d_in[6];
  const float* g1bl = (const float*)d_in[7];
  const float* g1Wr = (const float*)d_in[8];
  const float* g1br = (const float*)d_in[9];
  const float* g1att= (const float*)d_in[10];
  const float* g1bo = (const float*)d_in[11];
  const float* ln2g = (const float*)d_in[12];
  const float* ln2b = (const float*)d_in[13];
  const float* g2Wl = (const float*)d_in[14];
  const float* g2bl = (const float*)d_in[15];
  const float* g2Wr = (const float*)d_in[16];
  const float* g2br = (const float*)d_in[17];
  const float* g2att= (const float*)d_in[18];
  const float* g2bo = (const float*)d_in[19];
  const float* ln3g = (const float*)d_in[20];
  const float* ln3b = (const float*)d_in[21];
  const float* Ws1  = (const float*)d_in[22];
  const float* bs1  = (const float*)d_in[23];
  const float* Ws2  = (const float*)d_in[24];
  const float* bs2  = (const float*)d_in[25];
  const float* Ws3  = (const float*)d_in[26];
  const float* bs3  = (const float*)d_in[27];

  float* scores = (float*)d_out;
  float* h      = (float*)d_out + N_NODES;  // [N][1024] fp32, second output

  char* wsp = (char*)d_ws;
  size_t off = 0;
  auto alloc = [&](size_t bytes) -> char* {
    char* p = wsp + off;
    off += (bytes + 255) & ~(size_t)255;
    return p;
  };
  unsigned short* xb    = (unsigned short*)alloc((size_t)N_NODES * IN_DIM * 2);
  unsigned short* WinT  = (unsigned short*)alloc((size_t)HID * IN_DIM * 2);
  unsigned short* g1WlT = (unsigned short*)alloc((size_t)HID * HID * 2);
  unsigned short* g1WrT = (unsigned short*)alloc((size_t)HID * HID * 2);
  unsigned short* g2WlT = (unsigned short*)alloc((size_t)HID * HID * 2);
  unsigned short* g2WrT = (unsigned short*)alloc((size_t)HID * HID * 2);
  unsigned short* Ws1T  = (unsigned short*)alloc((size_t)512 * HID * 2);
  unsigned short* Ws2T  = (unsigned short*)alloc((size_t)128 * 512 * 2);
  unsigned short* hb    = (unsigned short*)alloc((size_t)N_NODES * HID * 2);
  unsigned short* s1b   = (unsigned short*)alloc((size_t)N_NODES * 512 * 2);
  unsigned short* xlb   = (unsigned short*)alloc((size_t)N_NODES * HID * 2);
  unsigned short* xrb   = (unsigned short*)alloc((size_t)N_NODES * HID * 2);
  float* C      = (float*)alloc((size_t)N_NODES * HID * 4);
  float* logits = (float*)alloc((size_t)ET * 8 * 4);
  float* alpha  = (float*)alloc((size_t)ET * 8 * 4);
  int* srcA     = (int*)alloc((size_t)ET * 4);
  int* dstA     = (int*)alloc((size_t)ET * 4);
  int* deg      = (int*)alloc(65536);
  int* cursor   = (int*)alloc(65536);
  int* rowstart = (int*)alloc(65544);
  int* src_csr  = (int*)alloc((size_t)ET * 4);
  int* dst_csr  = (int*)alloc((size_t)ET * 4);

  // --- weight/input conversions ---
  conv_bf16_kernel<<<(N_NODES * IN_DIM / 4 + 255) / 256, 256, 0, stream>>>(x, xb, N_NODES * IN_DIM / 4);
  dim3 tb(32, 8);
  transpose_conv_kernel<<<dim3(HID / 32, IN_DIM / 32), tb, 0, stream>>>(W_in, WinT, IN_DIM, HID);
  transpose_conv_kernel<<<dim3(HID / 32, HID / 32), tb, 0, stream>>>(g1Wl, g1WlT, HID, HID);
  transpose_conv_kernel<<<dim3(HID / 32, HID / 32), tb, 0, stream>>>(g1Wr, g1WrT, HID, HID);
  transpose_conv_kernel<<<dim3(HID / 32, HID / 32), tb, 0, stream>>>(g2Wl, g2WlT, HID, HID);
  transpose_conv_kernel<<<dim3(HID / 32, HID / 32), tb, 0, stream>>>(g2Wr, g2WrT, HID, HID);
  transpose_conv_kernel<<<dim3(512 / 32, HID / 32), tb, 0, stream>>>(Ws1, Ws1T, HID, 512);
  transpose_conv_kernel<<<dim3(128 / 32, 512 / 32), tb, 0, stream>>>(Ws2, Ws2T, 512, 128);

  // --- CSR build (shared by both GAT layers) ---
  hipMemsetAsync(deg, 0, 131072, stream);  // deg + cursor (contiguous)
  build_edges_kernel<<<ET / 256, 256, 0, stream>>>(ei, srcA, dstA, deg);
  scan16k_kernel<<<1, 1024, 0, stream>>>(deg, rowstart);
  scatter_edges_kernel<<<ET / 256, 256, 0, stream>>>(srcA, dstA, rowstart, cursor, src_csr, dst_csr);

  // --- input projection + LN1 + gelu ---
  gemm_bf16_kernel<0, 0><<<dim3(HID / 128, N_NODES / 128), 256, 0, stream>>>(
      xb, WinT, b_in, C, nullptr, N_NODES, HID, IN_DIM);
  ln_gelu_kernel<0><<<N_NODES, 256, 0, stream>>>(C, ln1g, ln1b, h, hb);

  // --- GAT layer 1 ---
  gemm_bf16_kernel<0, 2><<<dim3(HID / 128, N_NODES / 128), 256, 0, stream>>>(
      hb, g1WlT, g1bl, nullptr, xlb, N_NODES, HID, HID);
  gemm_bf16_kernel<0, 2><<<dim3(HID / 128, N_NODES / 128), 256, 0, stream>>>(
      hb, g1WrT, g1br, nullptr, xrb, N_NODES, HID, HID);
  edge_logits_kernel<<<ET / 4, 256, 0, stream>>>(xlb, xrb, g1att, src_csr, dst_csr, logits);
  alpha_kernel<<<N_NODES * 8 / 256, 256, 0, stream>>>(logits, rowstart, alpha);
  gat_aggregate_kernel<<<N_NODES, 256, 0, stream>>>(xlb, alpha, src_csr, rowstart, g1bo, C);
  ln_gelu_kernel<1><<<N_NODES, 256, 0, stream>>>(C, ln2g, ln2b, h, hb);

  // --- GAT layer 2 ---
  gemm_bf16_kernel<0, 2><<<dim3(HID / 128, N_NODES / 128), 256, 0, stream>>>(
      hb, g2WlT, g2bl, nullptr, xlb, N_NODES, HID, HID);
  gemm_bf16_kernel<0, 2><<<dim3(HID / 128, N_NODES / 128), 256, 0, stream>>>(
      hb, g2WrT, g2br, nullptr, xrb, N_NODES, HID, HID);
  edge_logits_kernel<<<ET / 4, 256, 0, stream>>>(xlb, xrb, g2att, src_csr, dst_csr, logits);
  alpha_kernel<<<N_NODES * 8 / 256, 256, 0, stream>>>(logits, rowstart, alpha);
  gat_aggregate_kernel<<<N_NODES, 256, 0, stream>>>(xlb, alpha, src_csr, rowstart, g2bo, C);
  ln_gelu_kernel<1><<<N_NODES, 256, 0, stream>>>(C, ln3g, ln3b, h, hb);

  // --- scorer MLP ---
  gemm_bf16_kernel<1, 2><<<dim3(512 / 128, N_NODES / 128), 256, 0, stream>>>(
      hb, Ws1T, bs1, nullptr, s1b, N_NODES, 512, HID);
  gemm_bf16_kernel<1, 0><<<dim3(128 / 128, N_NODES / 128), 256, 0, stream>>>(
      s1b, Ws2T, bs2, C, nullptr, N_NODES, 128, 512);
  score_kernel<<<N_NODES / 4, 256, 0, stream>>>(C, Ws3, bs3, scores);
}

// Round 3
// 651.545 us; speedup vs baseline: 1.6002x; 1.1184x over previous
//
#include <hip/hip_runtime.h>
#include <hip/hip_bf16.h>
#include <math.h>

#define N_NODES 16384
#define E_EDGES 65536
#define ET (E_EDGES + N_NODES)   /* 81920 edges incl self loops */
#define IN_DIM 1536
#define HID 1024

typedef __attribute__((ext_vector_type(8))) short bf16x8;
typedef __attribute__((ext_vector_type(4))) float f32x4;

__device__ __forceinline__ unsigned short f2b(float f) {
  unsigned int u = __float_as_uint(f);
  u = (u + 0x7FFFu + ((u >> 16) & 1u)) >> 16;
  return (unsigned short)u;
}

__device__ __forceinline__ float b2f(unsigned short u) {
  return __uint_as_float((unsigned int)u << 16);
}

__device__ __forceinline__ void gload_lds16(const void* g, void* l) {
  __builtin_amdgcn_global_load_lds((const __attribute__((address_space(1))) void*)g,
                                   (__attribute__((address_space(3))) void*)l, 16, 0, 0);
}

__device__ __forceinline__ float gelu_exact(float y) {
  return 0.5f * y * (1.0f + erff(y * 0.70710678118654752f));
}

// ---------------------------------------------------------------------------
// fp32 -> bf16 convert (vectorized)
__global__ void conv_bf16_kernel(const float* __restrict__ in, unsigned short* __restrict__ out, int n4) {
  int i = blockIdx.x * 256 + threadIdx.x;
  if (i < n4) {
    float4 v = ((const float4*)in)[i];
    ushort4 o;
    o.x = f2b(v.x); o.y = f2b(v.y); o.z = f2b(v.z); o.w = f2b(v.w);
    ((ushort4*)out)[i] = o;
  }
}

// transpose fp32 [K][N] -> bf16 [N][K]
__global__ void transpose_conv_kernel(const float* __restrict__ in, unsigned short* __restrict__ out,
                                      int K, int N) {
  __shared__ float tile[32][33];
  int bx = blockIdx.x * 32;  // n base
  int by = blockIdx.y * 32;  // k base
  int tx = threadIdx.x, ty = threadIdx.y;
  #pragma unroll
  for (int i = 0; i < 32; i += 8)
    tile[ty + i][tx] = in[(size_t)(by + ty + i) * N + bx + tx];
  __syncthreads();
  #pragma unroll
  for (int i = 0; i < 32; i += 8)
    out[(size_t)(bx + ty + i) * K + by + tx] = f2b(tile[tx][ty + i]);
}

// ---------------------------------------------------------------------------
// bf16 MFMA GEMM: C[M,N] = A[M,K](bf16) * Bt[N,K](bf16)^T + bias
// 128x128 tile, BK=64, 4 waves (2x2), each wave 64x64 via 4x4 16x16x32 MFMAs.
// LDS tiles XOR-swizzled (byte ^= (row&7)<<4) via pre-swizzled global source
// (linear global_load_lds dest) + swizzled ds_read addresses -> conflict-free.
// XCD-chunked tile remap: blocks sharing an A row-panel land on one XCD's L2.
// ACT: 0 none, 1 silu.  WB: 0 fp32 only, 1 fp32+bf16, 2 bf16 only.
template <int ACT, int WB>
__global__ __launch_bounds__(256)
void gemm_bf16_kernel(const unsigned short* __restrict__ A, const unsigned short* __restrict__ Bt,
                      const float* __restrict__ bias, float* __restrict__ C,
                      unsigned short* __restrict__ Cb, int M, int N, int K, int nx) {
  __shared__ unsigned short As[128 * 64];
  __shared__ unsigned short Bs[128 * 64];
  const int t = threadIdx.x;
  const int l = t & 63;
  const int w = t >> 6;
  const int wr = w >> 1, wc = w & 1;

  // XCD-aware bijective remap (gridDim.x % 8 == 0 for all shapes here)
  const int nwg = gridDim.x;
  const int cpx = nwg >> 3;
  const int bid = blockIdx.x;
  const int tile = (bid & 7) * cpx + (bid >> 3);
  const int bm = (tile / nx) * 128;
  const int bn = (tile % nx) * 128;

  f32x4 acc[4][4];
  #pragma unroll
  for (int m = 0; m < 4; m++)
    #pragma unroll
    for (int n = 0; n < 4; n++) acc[m][n] = (f32x4){0.f, 0.f, 0.f, 0.f};

  // staging: thread t loads 16B; per load i (0..3): row = (t>>3) + i*32,
  // source col bytes pre-swizzled by ((row&7)<<4) == ((t>>3)&7)<<4.
  const int srow = t >> 3;                                  // 0..31
  const int scolbsw = ((t & 7) * 16) ^ ((srow & 7) << 4);   // swizzled byte col
  const unsigned short* Ag = A + (size_t)(bm + srow) * K + (scolbsw >> 1);
  const unsigned short* Bg = Bt + (size_t)(bn + srow) * K + (scolbsw >> 1);

  const int ar = wr * 64 + (l & 15);
  const int br = wc * 64 + (l & 15);
  const int kk = (l >> 4) * 8;
  const int swA = (ar & 7) << 4;   // (row&7)<<4, constant across m (m*16 % 8 == 0)
  const int swB = (br & 7) << 4;
  const char* Asb = (const char*)As;
  const char* Bsb = (const char*)Bs;

  for (int k0 = 0; k0 < K; k0 += 64) {
    #pragma unroll
    for (int i = 0; i < 4; i++) {
      gload_lds16(Ag + (size_t)i * 32 * K + k0, (char*)As + t * 16 + i * 4096);
      gload_lds16(Bg + (size_t)i * 32 * K + k0, (char*)Bs + t * 16 + i * 4096);
    }
    __syncthreads();
    bf16x8 af[4], bfr[4];
    // k-half 0
    #pragma unroll
    for (int m = 0; m < 4; m++)
      af[m] = *(const bf16x8*)(Asb + (ar + m * 16) * 128 + ((kk * 2) ^ swA));
    #pragma unroll
    for (int n = 0; n < 4; n++)
      bfr[n] = *(const bf16x8*)(Bsb + (br + n * 16) * 128 + ((kk * 2) ^ swB));
    #pragma unroll
    for (int m = 0; m < 4; m++)
      #pragma unroll
      for (int n = 0; n < 4; n++)
        acc[m][n] = __builtin_amdgcn_mfma_f32_16x16x32_bf16(af[m], bfr[n], acc[m][n], 0, 0, 0);
    // k-half 1
    #pragma unroll
    for (int m = 0; m < 4; m++)
      af[m] = *(const bf16x8*)(Asb + (ar + m * 16) * 128 + ((kk * 2 + 64) ^ swA));
    #pragma unroll
    for (int n = 0; n < 4; n++)
      bfr[n] = *(const bf16x8*)(Bsb + (br + n * 16) * 128 + ((kk * 2 + 64) ^ swB));
    #pragma unroll
    for (int m = 0; m < 4; m++)
      #pragma unroll
      for (int n = 0; n < 4; n++)
        acc[m][n] = __builtin_amdgcn_mfma_f32_16x16x32_bf16(af[m], bfr[n], acc[m][n], 0, 0, 0);
    __syncthreads();
  }

  const int crow0 = bm + wr * 64 + (l >> 4) * 4;
  const int ccol0 = bn + wc * 64 + (l & 15);
  #pragma unroll
  for (int m = 0; m < 4; m++) {
    #pragma unroll
    for (int n = 0; n < 4; n++) {
      int col = ccol0 + n * 16;
      float bv = bias[col];
      #pragma unroll
      for (int v = 0; v < 4; v++) {
        int row = crow0 + m * 16 + v;
        float x = acc[m][n][v] + bv;
        if (ACT == 1) x = x / (1.0f + expf(-x));   // silu
        if (WB != 2) C[(size_t)row * N + col] = x;
        if (WB != 0) Cb[(size_t)row * N + col] = f2b(x);
      }
    }
  }
}

// ---------------------------------------------------------------------------
// layernorm + exact gelu (+ optional residual into h); writes h fp32 and bf16
template <int RES>
__global__ __launch_bounds__(256)
void ln_gelu_kernel(const float* __restrict__ c, const float* __restrict__ g,
                    const float* __restrict__ b, float* __restrict__ h,
                    unsigned short* __restrict__ hb) {
  int row = blockIdx.x;
  int t = threadIdx.x;
  const float* cr = c + (size_t)row * HID;
  float v[4];
  float s = 0.f, q = 0.f;
  #pragma unroll
  for (int j = 0; j < 4; j++) {
    v[j] = cr[t + 256 * j];
    s += v[j];
    q += v[j] * v[j];
  }
  #pragma unroll
  for (int off = 32; off; off >>= 1) {
    s += __shfl_xor(s, off);
    q += __shfl_xor(q, off);
  }
  __shared__ float rs[4], rq[4];
  int wv = t >> 6, l = t & 63;
  if (l == 0) { rs[wv] = s; rq[wv] = q; }
  __syncthreads();
  s = rs[0] + rs[1] + rs[2] + rs[3];
  q = rq[0] + rq[1] + rq[2] + rq[3];
  float mu = s * (1.0f / HID);
  float var = q * (1.0f / HID) - mu * mu;
  float rstd = rsqrtf(var + 1e-5f);
  float* hr = h + (size_t)row * HID;
  unsigned short* hbr = hb + (size_t)row * HID;
  #pragma unroll
  for (int j = 0; j < 4; j++) {
    int ci = t + 256 * j;
    float y = (v[j] - mu) * rstd * g[ci] + b[ci];
    float z = gelu_exact(y);
    float o = RES ? (hr[ci] + z) : z;
    hr[ci] = o;
    hbr[ci] = f2b(o);
  }
}

// ---------------------------------------------------------------------------
// edge list build (+ self loops) and dst-degree histogram
__global__ void build_edges_kernel(const int* __restrict__ ei, int* __restrict__ srcA,
                                   int* __restrict__ dstA, int* __restrict__ deg) {
  int i = blockIdx.x * 256 + threadIdx.x;
  if (i >= ET) return;
  int s, d;
  if (i < E_EDGES) { s = ei[i]; d = ei[E_EDGES + i]; }
  else             { s = i - E_EDGES; d = s; }
  srcA[i] = s;
  dstA[i] = d;
  atomicAdd(&deg[d], 1);
}

// exclusive scan of 16384 degrees, single block of 1024 threads
__global__ __launch_bounds__(1024)
void scan16k_kernel(const int* __restrict__ deg, int* __restrict__ rowstart) {
  __shared__ int s[1024];
  int t = threadIdx.x;
  int local[16];
  int sum = 0;
  #pragma unroll
  for (int i = 0; i < 16; i++) { local[i] = deg[t * 16 + i]; sum += local[i]; }
  s[t] = sum;
  __syncthreads();
  for (int off = 1; off < 1024; off <<= 1) {
    int v = (t >= off) ? s[t - off] : 0;
    __syncthreads();
    s[t] += v;
    __syncthreads();
  }
  int run = s[t] - sum;
  #pragma unroll
  for (int i = 0; i < 16; i++) { rowstart[t * 16 + i] = run; run += local[i]; }
  if (t == 1023) rowstart[16384] = run;
}

// scatter edges into CSR slots; store src and dst per CSR position
__global__ void scatter_edges_kernel(const int* __restrict__ srcA, const int* __restrict__ dstA,
                                     const int* __restrict__ rowstart, int* __restrict__ cursor,
                                     int* __restrict__ src_csr, int* __restrict__ dst_csr) {
  int i = blockIdx.x * 256 + threadIdx.x;
  if (i >= ET) return;
  int d = dstA[i];
  int pos = atomicAdd(&cursor[d], 1);
  int p = rowstart[d] + pos;
  src_csr[p] = srcA[i];
  dst_csr[p] = d;
}

// ---------------------------------------------------------------------------
// per-edge attention logits over CSR order (consecutive waves share dst row).
// One wave per CSR slot; lane l covers channels [16l, 16l+16).
__global__ __launch_bounds__(256)
void edge_logits_kernel(const unsigned short* __restrict__ xl, const unsigned short* __restrict__ xr,
                        const float* __restrict__ att, const int* __restrict__ src_csr,
                        const int* __restrict__ dst_csr, float* __restrict__ logits) {
  int e = blockIdx.x * 4 + (threadIdx.x >> 6);
  int l = threadIdx.x & 63;
  int s = src_csr[e], d = dst_csr[e];
  const unsigned short* xls = xl + (size_t)s * HID + l * 16;
  const unsigned short* xrd = xr + (size_t)d * HID + l * 16;
  bf16x8 a0 = *(const bf16x8*)xls;
  bf16x8 a1 = *(const bf16x8*)(xls + 8);
  bf16x8 b0 = *(const bf16x8*)xrd;
  bf16x8 b1 = *(const bf16x8*)(xrd + 8);
  const float* ac = att + l * 16;
  float p = 0.f;
  #pragma unroll
  for (int j = 0; j < 8; j++) {
    float u = b2f((unsigned short)a0[j]) + b2f((unsigned short)b0[j]);
    float v = b2f((unsigned short)a1[j]) + b2f((unsigned short)b1[j]);
    u = u > 0.f ? u : 0.2f * u;
    v = v > 0.f ? v : 0.2f * v;
    p += u * ac[j] + v * ac[j + 8];
  }
  p += __shfl_xor(p, 1);
  p += __shfl_xor(p, 2);
  p += __shfl_xor(p, 4);
  if ((l & 7) == 0) logits[(size_t)e * 8 + (l >> 3)] = p;
}

// per-(node,head) softmax over CSR-contiguous logits -> alpha
__global__ __launch_bounds__(256)
void alpha_kernel(const float* __restrict__ logits, const int* __restrict__ rowstart,
                  float* __restrict__ alpha) {
  int gid = blockIdx.x * 256 + threadIdx.x;
  if (gid >= N_NODES * 8) return;
  int nid = gid >> 3, hh = gid & 7;
  int beg = rowstart[nid], end = rowstart[nid + 1];
  float m = -1e30f;
  for (int i = beg; i < end; i++) m = fmaxf(m, logits[(size_t)i * 8 + hh]);
  float den = 0.f;
  for (int i = beg; i < end; i++) den += expf(logits[(size_t)i * 8 + hh] - m);
  float inv = 1.0f / den;
  for (int i = beg; i < end; i++) alpha[(size_t)i * 8 + hh] = expf(logits[(size_t)i * 8 + hh] - m) * inv;
}

// per-dst aggregate: out[n] = sum_e alpha[e]*xl[src_e] + bo   (bf16 gathers)
__global__ __launch_bounds__(256)
void gat_aggregate_kernel(const unsigned short* __restrict__ xl, const float* __restrict__ alpha,
                          const int* __restrict__ src_csr, const int* __restrict__ rowstart,
                          const float* __restrict__ bo, float* __restrict__ out) {
  int nid = blockIdx.x;
  int beg = rowstart[nid], end = rowstart[nid + 1];
  int t = threadIdx.x;
  int c0 = t * 4;
  int hh = t >> 5;          // c0>>7
  float acc0 = 0.f, acc1 = 0.f, acc2 = 0.f, acc3 = 0.f;
  for (int i = beg; i < end; i++) {
    float a = alpha[(size_t)i * 8 + hh];
    int s = src_csr[i];
    ushort4 v = *(const ushort4*)(xl + (size_t)s * HID + c0);
    acc0 += a * b2f(v.x);
    acc1 += a * b2f(v.y);
    acc2 += a * b2f(v.z);
    acc3 += a * b2f(v.w);
  }
  const float4 bv = *(const float4*)(bo + c0);
  float4 o;
  o.x = acc0 + bv.x; o.y = acc1 + bv.y; o.z = acc2 + bv.z; o.w = acc3 + bv.w;
  *(float4*)(out + (size_t)nid * HID + c0) = o;
}

// final scorer dot: scores[n] = dot(s2[n][0:128], Ws3) + bs3
__global__ __launch_bounds__(256)
void score_kernel(const float* __restrict__ s2, const float* __restrict__ Ws3,
                  const float* __restrict__ bs3, float* __restrict__ out) {
  int nid = blockIdx.x * 4 + (threadIdx.x >> 6);
  int l = threadIdx.x & 63;
  const float* r = s2 + (size_t)nid * 128;
  float a = r[l] * Ws3[l] + r[l + 64] * Ws3[l + 64];
  #pragma unroll
  for (int off = 32; off; off >>= 1) a += __shfl_xor(a, off);
  if (l == 0) out[nid] = a + bs3[0];
}

// ---------------------------------------------------------------------------
extern "C" void kernel_launch(void* const* d_in, const int* in_sizes, int n_in,
                              void* d_out, int out_size, void* d_ws, size_t ws_size,
                              hipStream_t stream) {
  const float* x    = (const float*)d_in[0];
  const int*   ei   = (const int*)  d_in[1];
  const float* W_in = (const float*)d_in[2];
  const float* b_in = (const float*)d_in[3];
  const float* ln1g = (const float*)d_in[4];
  const float* ln1b = (const float*)d_in[5];
  const float* g1Wl = (const float*)d_in[6];
  const float* g1bl = (const float*)d_in[7];
  const float* g1Wr = (const float*)d_in[8];
  const float* g1br = (const float*)d_in[9];
  const float* g1att= (const float*)d_in[10];
  const float* g1bo = (const float*)d_in[11];
  const float* ln2g = (const float*)d_in[12];
  const float* ln2b = (const float*)d_in[13];
  const float* g2Wl = (const float*)d_in[14];
  const float* g2bl = (const float*)d_in[15];
  const float* g2Wr = (const float*)d_in[16];
  const float* g2br = (const float*)d_in[17];
  const float* g2att= (const float*)d_in[18];
  const float* g2bo = (const float*)d_in[19];
  const float* ln3g = (const float*)d_in[20];
  const float* ln3b = (const float*)d_in[21];
  const float* Ws1  = (const float*)d_in[22];
  const float* bs1  = (const float*)d_in[23];
  const float* Ws2  = (const float*)d_in[24];
  const float* bs2  = (const float*)d_in[25];
  const float* Ws3  = (const float*)d_in[26];
  const float* bs3  = (const float*)d_in[27];

  float* scores = (float*)d_out;
  float* h      = (float*)d_out + N_NODES;  // [N][1024] fp32, second output

  char* wsp = (char*)d_ws;
  size_t off = 0;
  auto alloc = [&](size_t bytes) -> char* {
    char* p = wsp + off;
    off += (bytes + 255) & ~(size_t)255;
    return p;
  };
  unsigned short* xb    = (unsigned short*)alloc((size_t)N_NODES * IN_DIM * 2);
  unsigned short* WinT  = (unsigned short*)alloc((size_t)HID * IN_DIM * 2);
  unsigned short* g1WlT = (unsigned short*)alloc((size_t)HID * HID * 2);
  unsigned short* g1WrT = (unsigned short*)alloc((size_t)HID * HID * 2);
  unsigned short* g2WlT = (unsigned short*)alloc((size_t)HID * HID * 2);
  unsigned short* g2WrT = (unsigned short*)alloc((size_t)HID * HID * 2);
  unsigned short* Ws1T  = (unsigned short*)alloc((size_t)512 * HID * 2);
  unsigned short* Ws2T  = (unsigned short*)alloc((size_t)128 * 512 * 2);
  unsigned short* hb    = (unsigned short*)alloc((size_t)N_NODES * HID * 2);
  unsigned short* s1b   = (unsigned short*)alloc((size_t)N_NODES * 512 * 2);
  unsigned short* xlb   = (unsigned short*)alloc((size_t)N_NODES * HID * 2);
  unsigned short* xrb   = (unsigned short*)alloc((size_t)N_NODES * HID * 2);
  float* C      = (float*)alloc((size_t)N_NODES * HID * 4);
  float* logits = (float*)alloc((size_t)ET * 8 * 4);
  float* alpha  = (float*)alloc((size_t)ET * 8 * 4);
  int* srcA     = (int*)alloc((size_t)ET * 4);
  int* dstA     = (int*)alloc((size_t)ET * 4);
  int* deg      = (int*)alloc(65536);
  int* cursor   = (int*)alloc(65536);
  int* rowstart = (int*)alloc(65544);
  int* src_csr  = (int*)alloc((size_t)ET * 4);
  int* dst_csr  = (int*)alloc((size_t)ET * 4);

  // --- weight/input conversions ---
  conv_bf16_kernel<<<(N_NODES * IN_DIM / 4 + 255) / 256, 256, 0, stream>>>(x, xb, N_NODES * IN_DIM / 4);
  dim3 tb(32, 8);
  transpose_conv_kernel<<<dim3(HID / 32, IN_DIM / 32), tb, 0, stream>>>(W_in, WinT, IN_DIM, HID);
  transpose_conv_kernel<<<dim3(HID / 32, HID / 32), tb, 0, stream>>>(g1Wl, g1WlT, HID, HID);
  transpose_conv_kernel<<<dim3(HID / 32, HID / 32), tb, 0, stream>>>(g1Wr, g1WrT, HID, HID);
  transpose_conv_kernel<<<dim3(HID / 32, HID / 32), tb, 0, stream>>>(g2Wl, g2WlT, HID, HID);
  transpose_conv_kernel<<<dim3(HID / 32, HID / 32), tb, 0, stream>>>(g2Wr, g2WrT, HID, HID);
  transpose_conv_kernel<<<dim3(512 / 32, HID / 32), tb, 0, stream>>>(Ws1, Ws1T, HID, 512);
  transpose_conv_kernel<<<dim3(128 / 32, 512 / 32), tb, 0, stream>>>(Ws2, Ws2T, 512, 128);

  // --- CSR build (shared by both GAT layers) ---
  hipMemsetAsync(deg, 0, 131072, stream);  // deg + cursor (contiguous)
  build_edges_kernel<<<ET / 256, 256, 0, stream>>>(ei, srcA, dstA, deg);
  scan16k_kernel<<<1, 1024, 0, stream>>>(deg, rowstart);
  scatter_edges_kernel<<<ET / 256, 256, 0, stream>>>(srcA, dstA, rowstart, cursor, src_csr, dst_csr);

  // --- input projection + LN1 + gelu ---
  gemm_bf16_kernel<0, 0><<<8 * 128, 256, 0, stream>>>(
      xb, WinT, b_in, C, nullptr, N_NODES, HID, IN_DIM, 8);
  ln_gelu_kernel<0><<<N_NODES, 256, 0, stream>>>(C, ln1g, ln1b, h, hb);

  // --- GAT layer 1 ---
  gemm_bf16_kernel<0, 2><<<8 * 128, 256, 0, stream>>>(
      hb, g1WlT, g1bl, nullptr, xlb, N_NODES, HID, HID, 8);
  gemm_bf16_kernel<0, 2><<<8 * 128, 256, 0, stream>>>(
      hb, g1WrT, g1br, nullptr, xrb, N_NODES, HID, HID, 8);
  edge_logits_kernel<<<ET / 4, 256, 0, stream>>>(xlb, xrb, g1att, src_csr, dst_csr, logits);
  alpha_kernel<<<N_NODES * 8 / 256, 256, 0, stream>>>(logits, rowstart, alpha);
  gat_aggregate_kernel<<<N_NODES, 256, 0, stream>>>(xlb, alpha, src_csr, rowstart, g1bo, C);
  ln_gelu_kernel<1><<<N_NODES, 256, 0, stream>>>(C, ln2g, ln2b, h, hb);

  // --- GAT layer 2 ---
  gemm_bf16_kernel<0, 2><<<8 * 128, 256, 0, stream>>>(
      hb, g2WlT, g2bl, nullptr, xlb, N_NODES, HID, HID, 8);
  gemm_bf16_kernel<0, 2><<<8 * 128, 256, 0, stream>>>(
      hb, g2WrT, g2br, nullptr, xrb, N_NODES, HID, HID, 8);
  edge_logits_kernel<<<ET / 4, 256, 0, stream>>>(xlb, xrb, g2att, src_csr, dst_csr, logits);
  alpha_kernel<<<N_NODES * 8 / 256, 256, 0, stream>>>(logits, rowstart, alpha);
  gat_aggregate_kernel<<<N_NODES, 256, 0, stream>>>(xlb, alpha, src_csr, rowstart, g2bo, C);
  ln_gelu_kernel<1><<<N_NODES, 256, 0, stream>>>(C, ln3g, ln3b, h, hb);

  // --- scorer MLP ---
  gemm_bf16_kernel<1, 2><<<4 * 128, 256, 0, stream>>>(
      hb, Ws1T, bs1, nullptr, s1b, N_NODES, 512, HID, 4);
  gemm_bf16_kernel<1, 0><<<1 * 128, 256, 0, stream>>>(
      s1b, Ws2T, bs2, C, nullptr, N_NODES, 128, 512, 1);
  score_kernel<<<N_NODES / 4, 256, 0, stream>>>(C, Ws3, bs3, scores);
}

// Round 4
// 576.375 us; speedup vs baseline: 1.8089x; 1.1304x over previous
//
#include <hip/hip_runtime.h>
#include <hip/hip_bf16.h>
#include <math.h>

#define N_NODES 16384
#define E_EDGES 65536
#define ET (E_EDGES + N_NODES)   /* 81920 edges incl self loops */
#define IN_DIM 1536
#define HID 1024
#define XSTR 2048                /* fused xl|xr row stride */

typedef __attribute__((ext_vector_type(8))) short bf16x8;
typedef __attribute__((ext_vector_type(4))) float f32x4;

__device__ __forceinline__ unsigned short f2b(float f) {
  unsigned int u = __float_as_uint(f);
  u = (u + 0x7FFFu + ((u >> 16) & 1u)) >> 16;
  return (unsigned short)u;
}

__device__ __forceinline__ float b2f(unsigned short u) {
  return __uint_as_float((unsigned int)u << 16);
}

__device__ __forceinline__ void gload_lds16(const void* g, void* l) {
  __builtin_amdgcn_global_load_lds((const __attribute__((address_space(1))) void*)g,
                                   (__attribute__((address_space(3))) void*)l, 16, 0, 0);
}

__device__ __forceinline__ float gelu_exact(float y) {
  return 0.5f * y * (1.0f + erff(y * 0.70710678118654752f));
}

// ---------------------------------------------------------------------------
// fp32 -> bf16 convert (vectorized)
__global__ void conv_bf16_kernel(const float* __restrict__ in, unsigned short* __restrict__ out, int n4) {
  int i = blockIdx.x * 256 + threadIdx.x;
  if (i < n4) {
    float4 v = ((const float4*)in)[i];
    ushort4 o;
    o.x = f2b(v.x); o.y = f2b(v.y); o.z = f2b(v.z); o.w = f2b(v.w);
    ((ushort4*)out)[i] = o;
  }
}

// transpose fp32 [K][N] -> bf16 [N][K]
__global__ void transpose_conv_kernel(const float* __restrict__ in, unsigned short* __restrict__ out,
                                      int K, int N) {
  __shared__ float tile[32][33];
  int bx = blockIdx.x * 32;  // n base
  int by = blockIdx.y * 32;  // k base
  int tx = threadIdx.x, ty = threadIdx.y;
  #pragma unroll
  for (int i = 0; i < 32; i += 8)
    tile[ty + i][tx] = in[(size_t)(by + ty + i) * N + bx + tx];
  __syncthreads();
  #pragma unroll
  for (int i = 0; i < 32; i += 8)
    out[(size_t)(bx + ty + i) * K + by + tx] = f2b(tile[tx][ty + i]);
}

// concat two float vectors [n] -> [2n]
__global__ void concat2_kernel(const float* __restrict__ a, const float* __restrict__ b,
                               float* __restrict__ o, int n) {
  int i = blockIdx.x * 256 + threadIdx.x;
  if (i < n) o[i] = a[i];
  else if (i < 2 * n) o[i] = b[i - n];
}

// ---------------------------------------------------------------------------
// bf16 MFMA GEMM: C[M,N] = A[M,K](bf16) * Bt[N,K](bf16)^T + bias
// 256x128 tile, BK=64, 8 waves (4x2), each wave 64x64 via 4x4 16x16x32 MFMAs.
// LDS XOR-swizzled (byte ^= (row&7)<<4) via pre-swizzled global source
// (linear global_load_lds dest) + swizzled ds_read addresses -> conflict-free.
// XCD-chunked tile remap. ACT: 0 none, 1 silu.  WB: 0 fp32, 2 bf16 only.
template <int ACT, int WB>
__global__ __launch_bounds__(512)
void gemm_bf16_kernel(const unsigned short* __restrict__ A, const unsigned short* __restrict__ Bt,
                      const float* __restrict__ bias, float* __restrict__ C,
                      unsigned short* __restrict__ Cb, int M, int N, int K, int nx) {
  __shared__ unsigned short As[256 * 64];
  __shared__ unsigned short Bs[128 * 64];
  const int t = threadIdx.x;
  const int l = t & 63;
  const int w = t >> 6;            // 0..7
  const int wr = w >> 1, wc = w & 1;

  // XCD-aware bijective remap (gridDim.x % 8 == 0 for all shapes here)
  const int nwg = gridDim.x;
  const int cpx = nwg >> 3;
  const int bid = blockIdx.x;
  const int tile = (bid & 7) * cpx + (bid >> 3);
  const int bm = (tile / nx) * 256;
  const int bn = (tile % nx) * 128;

  f32x4 acc[4][4];
  #pragma unroll
  for (int m = 0; m < 4; m++)
    #pragma unroll
    for (int n = 0; n < 4; n++) acc[m][n] = (f32x4){0.f, 0.f, 0.f, 0.f};

  // staging: thread t loads 16B chunks; row = (t>>3) + i*64,
  // source col bytes pre-swizzled by ((row&7)<<4) (row&7 == (t>>3)&7).
  const int srow = t >> 3;                                  // 0..63
  const int scolbsw = ((t & 7) * 16) ^ ((srow & 7) << 4);   // swizzled byte col
  const unsigned short* Ag = A + (size_t)(bm + srow) * K + (scolbsw >> 1);
  const unsigned short* Bg = Bt + (size_t)(bn + srow) * K + (scolbsw >> 1);

  const int ar = wr * 64 + (l & 15);        // 0..255
  const int br = wc * 64 + (l & 15);        // 0..127
  const int kk2 = (l >> 4) * 16;            // k-fragment byte offset
  const int swA = (ar & 7) << 4;            // constant across m (m*16 % 8 == 0)
  const int swB = (br & 7) << 4;
  const char* Asb = (const char*)As;
  const char* Bsb = (const char*)Bs;

  for (int k0 = 0; k0 < K; k0 += 64) {
    #pragma unroll
    for (int i = 0; i < 4; i++)
      gload_lds16(Ag + (size_t)i * 64 * K + k0, (char*)As + t * 16 + i * 8192);
    #pragma unroll
    for (int i = 0; i < 2; i++)
      gload_lds16(Bg + (size_t)i * 64 * K + k0, (char*)Bs + t * 16 + i * 8192);
    __syncthreads();
    bf16x8 af[4], bfr[4];
    // k-half 0
    #pragma unroll
    for (int m = 0; m < 4; m++)
      af[m] = *(const bf16x8*)(Asb + (ar + m * 16) * 128 + (kk2 ^ swA));
    #pragma unroll
    for (int n = 0; n < 4; n++)
      bfr[n] = *(const bf16x8*)(Bsb + (br + n * 16) * 128 + (kk2 ^ swB));
    #pragma unroll
    for (int m = 0; m < 4; m++)
      #pragma unroll
      for (int n = 0; n < 4; n++)
        acc[m][n] = __builtin_amdgcn_mfma_f32_16x16x32_bf16(af[m], bfr[n], acc[m][n], 0, 0, 0);
    // k-half 1
    #pragma unroll
    for (int m = 0; m < 4; m++)
      af[m] = *(const bf16x8*)(Asb + (ar + m * 16) * 128 + ((kk2 + 64) ^ swA));
    #pragma unroll
    for (int n = 0; n < 4; n++)
      bfr[n] = *(const bf16x8*)(Bsb + (br + n * 16) * 128 + ((kk2 + 64) ^ swB));
    #pragma unroll
    for (int m = 0; m < 4; m++)
      #pragma unroll
      for (int n = 0; n < 4; n++)
        acc[m][n] = __builtin_amdgcn_mfma_f32_16x16x32_bf16(af[m], bfr[n], acc[m][n], 0, 0, 0);
    __syncthreads();
  }

  const int crow0 = bm + wr * 64 + (l >> 4) * 4;
  const int ccol0 = bn + wc * 64 + (l & 15);
  #pragma unroll
  for (int m = 0; m < 4; m++) {
    #pragma unroll
    for (int n = 0; n < 4; n++) {
      int col = ccol0 + n * 16;
      float bv = bias[col];
      #pragma unroll
      for (int v = 0; v < 4; v++) {
        int row = crow0 + m * 16 + v;
        float x = acc[m][n][v] + bv;
        if (ACT == 1) x = x / (1.0f + expf(-x));   // silu
        if (WB != 2) C[(size_t)row * N + col] = x;
        if (WB != 0) Cb[(size_t)row * N + col] = f2b(x);
      }
    }
  }
}

// ---------------------------------------------------------------------------
// layernorm + exact gelu (+ optional residual into h); writes h fp32 and bf16
template <int RES>
__global__ __launch_bounds__(256)
void ln_gelu_kernel(const float* __restrict__ c, const float* __restrict__ g,
                    const float* __restrict__ b, float* __restrict__ h,
                    unsigned short* __restrict__ hb) {
  int row = blockIdx.x;
  int t = threadIdx.x;
  const float* cr = c + (size_t)row * HID;
  float v[4];
  float s = 0.f, q = 0.f;
  #pragma unroll
  for (int j = 0; j < 4; j++) {
    v[j] = cr[t + 256 * j];
    s += v[j];
    q += v[j] * v[j];
  }
  #pragma unroll
  for (int off = 32; off; off >>= 1) {
    s += __shfl_xor(s, off);
    q += __shfl_xor(q, off);
  }
  __shared__ float rs[4], rq[4];
  int wv = t >> 6, l = t & 63;
  if (l == 0) { rs[wv] = s; rq[wv] = q; }
  __syncthreads();
  s = rs[0] + rs[1] + rs[2] + rs[3];
  q = rq[0] + rq[1] + rq[2] + rq[3];
  float mu = s * (1.0f / HID);
  float var = q * (1.0f / HID) - mu * mu;
  float rstd = rsqrtf(var + 1e-5f);
  float* hr = h + (size_t)row * HID;
  unsigned short* hbr = hb + (size_t)row * HID;
  #pragma unroll
  for (int j = 0; j < 4; j++) {
    int ci = t + 256 * j;
    float y = (v[j] - mu) * rstd * g[ci] + b[ci];
    float z = gelu_exact(y);
    float o = RES ? (hr[ci] + z) : z;
    hr[ci] = o;
    hbr[ci] = f2b(o);
  }
}

// ---------------------------------------------------------------------------
// edge list build (+ self loops) and dst-degree histogram
__global__ void build_edges_kernel(const int* __restrict__ ei, int* __restrict__ srcA,
                                   int* __restrict__ dstA, int* __restrict__ deg) {
  int i = blockIdx.x * 256 + threadIdx.x;
  if (i >= ET) return;
  int s, d;
  if (i < E_EDGES) { s = ei[i]; d = ei[E_EDGES + i]; }
  else             { s = i - E_EDGES; d = s; }
  srcA[i] = s;
  dstA[i] = d;
  atomicAdd(&deg[d], 1);
}

// exclusive scan of 16384 degrees, single block of 1024 threads
__global__ __launch_bounds__(1024)
void scan16k_kernel(const int* __restrict__ deg, int* __restrict__ rowstart) {
  __shared__ int s[1024];
  int t = threadIdx.x;
  int local[16];
  int sum = 0;
  #pragma unroll
  for (int i = 0; i < 16; i++) { local[i] = deg[t * 16 + i]; sum += local[i]; }
  s[t] = sum;
  __syncthreads();
  for (int off = 1; off < 1024; off <<= 1) {
    int v = (t >= off) ? s[t - off] : 0;
    __syncthreads();
    s[t] += v;
    __syncthreads();
  }
  int run = s[t] - sum;
  #pragma unroll
  for (int i = 0; i < 16; i++) { rowstart[t * 16 + i] = run; run += local[i]; }
  if (t == 1023) rowstart[16384] = run;
}

// scatter edges into CSR slots; store src and dst per CSR position
__global__ void scatter_edges_kernel(const int* __restrict__ srcA, const int* __restrict__ dstA,
                                     const int* __restrict__ rowstart, int* __restrict__ cursor,
                                     int* __restrict__ src_csr, int* __restrict__ dst_csr) {
  int i = blockIdx.x * 256 + threadIdx.x;
  if (i >= ET) return;
  int d = dstA[i];
  int pos = atomicAdd(&cursor[d], 1);
  int p = rowstart[d] + pos;
  src_csr[p] = srcA[i];
  dst_csr[p] = d;
}

// ---------------------------------------------------------------------------
// per-edge attention logits over CSR order (consecutive waves share dst row).
// xe = fused [N][2048] bf16: cols 0..1023 = xl, 1024..2047 = xr.
__global__ __launch_bounds__(256)
void edge_logits_kernel(const unsigned short* __restrict__ xe,
                        const float* __restrict__ att, const int* __restrict__ src_csr,
                        const int* __restrict__ dst_csr, float* __restrict__ logits) {
  int e = blockIdx.x * 4 + (threadIdx.x >> 6);
  int l = threadIdx.x & 63;
  int s = src_csr[e], d = dst_csr[e];
  const unsigned short* xls = xe + (size_t)s * XSTR + l * 16;
  const unsigned short* xrd = xe + (size_t)d * XSTR + 1024 + l * 16;
  bf16x8 a0 = *(const bf16x8*)xls;
  bf16x8 a1 = *(const bf16x8*)(xls + 8);
  bf16x8 b0 = *(const bf16x8*)xrd;
  bf16x8 b1 = *(const bf16x8*)(xrd + 8);
  const float* ac = att + l * 16;
  float p = 0.f;
  #pragma unroll
  for (int j = 0; j < 8; j++) {
    float u = b2f((unsigned short)a0[j]) + b2f((unsigned short)b0[j]);
    float v = b2f((unsigned short)a1[j]) + b2f((unsigned short)b1[j]);
    u = u > 0.f ? u : 0.2f * u;
    v = v > 0.f ? v : 0.2f * v;
    p += u * ac[j] + v * ac[j + 8];
  }
  p += __shfl_xor(p, 1);
  p += __shfl_xor(p, 2);
  p += __shfl_xor(p, 4);
  if ((l & 7) == 0) logits[(size_t)e * 8 + (l >> 3)] = p;
}

// per-(node,head) softmax over CSR-contiguous logits -> alpha
__global__ __launch_bounds__(256)
void alpha_kernel(const float* __restrict__ logits, const int* __restrict__ rowstart,
                  float* __restrict__ alpha) {
  int gid = blockIdx.x * 256 + threadIdx.x;
  if (gid >= N_NODES * 8) return;
  int nid = gid >> 3, hh = gid & 7;
  int beg = rowstart[nid], end = rowstart[nid + 1];
  float m = -1e30f;
  for (int i = beg; i < end; i++) m = fmaxf(m, logits[(size_t)i * 8 + hh]);
  float den = 0.f;
  for (int i = beg; i < end; i++) den += expf(logits[(size_t)i * 8 + hh] - m);
  float inv = 1.0f / den;
  for (int i = beg; i < end; i++) alpha[(size_t)i * 8 + hh] = expf(logits[(size_t)i * 8 + hh] - m) * inv;
}

// per-dst aggregate: out[n] = sum_e alpha[e]*xl[src_e] + bo   (bf16 gathers)
__global__ __launch_bounds__(256)
void gat_aggregate_kernel(const unsigned short* __restrict__ xe, const float* __restrict__ alpha,
                          const int* __restrict__ src_csr, const int* __restrict__ rowstart,
                          const float* __restrict__ bo, float* __restrict__ out) {
  int nid = blockIdx.x;
  int beg = rowstart[nid], end = rowstart[nid + 1];
  int t = threadIdx.x;
  int c0 = t * 4;
  int hh = t >> 5;          // c0>>7
  float acc0 = 0.f, acc1 = 0.f, acc2 = 0.f, acc3 = 0.f;
  for (int i = beg; i < end; i++) {
    float a = alpha[(size_t)i * 8 + hh];
    int s = src_csr[i];
    ushort4 v = *(const ushort4*)(xe + (size_t)s * XSTR + c0);
    acc0 += a * b2f(v.x);
    acc1 += a * b2f(v.y);
    acc2 += a * b2f(v.z);
    acc3 += a * b2f(v.w);
  }
  const float4 bv = *(const float4*)(bo + c0);
  float4 o;
  o.x = acc0 + bv.x; o.y = acc1 + bv.y; o.z = acc2 + bv.z; o.w = acc3 + bv.w;
  *(float4*)(out + (size_t)nid * HID + c0) = o;
}

// final scorer dot: scores[n] = dot(s2[n][0:128], Ws3) + bs3
__global__ __launch_bounds__(256)
void score_kernel(const float* __restrict__ s2, const float* __restrict__ Ws3,
                  const float* __restrict__ bs3, float* __restrict__ out) {
  int nid = blockIdx.x * 4 + (threadIdx.x >> 6);
  int l = threadIdx.x & 63;
  const float* r = s2 + (size_t)nid * 128;
  float a = r[l] * Ws3[l] + r[l + 64] * Ws3[l + 64];
  #pragma unroll
  for (int off = 32; off; off >>= 1) a += __shfl_xor(a, off);
  if (l == 0) out[nid] = a + bs3[0];
}

// ---------------------------------------------------------------------------
extern "C" void kernel_launch(void* const* d_in, const int* in_sizes, int n_in,
                              void* d_out, int out_size, void* d_ws, size_t ws_size,
                              hipStream_t stream) {
  const float* x    = (const float*)d_in[0];
  const int*   ei   = (const int*)  d_in[1];
  const float* W_in = (const float*)d_in[2];
  const float* b_in = (const float*)d_in[3];
  const float* ln1g = (const float*)d_in[4];
  const float* ln1b = (const float*)d_in[5];
  const float* g1Wl = (const float*)d_in[6];
  const float* g1bl = (const float*)d_in[7];
  const float* g1Wr = (const float*)d_in[8];
  const float* g1br = (const float*)d_in[9];
  const float* g1att= (const float*)d_in[10];
  const float* g1bo = (const float*)d_in[11];
  const float* ln2g = (const float*)d_in[12];
  const float* ln2b = (const float*)d_in[13];
  const float* g2Wl = (const float*)d_in[14];
  const float* g2bl = (const float*)d_in[15];
  const float* g2Wr = (const float*)d_in[16];
  const float* g2br = (const float*)d_in[17];
  const float* g2att= (const float*)d_in[18];
  const float* g2bo = (const float*)d_in[19];
  const float* ln3g = (const float*)d_in[20];
  const float* ln3b = (const float*)d_in[21];
  const float* Ws1  = (const float*)d_in[22];
  const float* bs1  = (const float*)d_in[23];
  const float* Ws2  = (const float*)d_in[24];
  const float* bs2  = (const float*)d_in[25];
  const float* Ws3  = (const float*)d_in[26];
  const float* bs3  = (const float*)d_in[27];

  float* scores = (float*)d_out;
  float* h      = (float*)d_out + N_NODES;  // [N][1024] fp32, second output

  char* wsp = (char*)d_ws;
  size_t off = 0;
  auto alloc = [&](size_t bytes) -> char* {
    char* p = wsp + off;
    off += (bytes + 255) & ~(size_t)255;
    return p;
  };
  unsigned short* xb    = (unsigned short*)alloc((size_t)N_NODES * IN_DIM * 2);
  unsigned short* WinT  = (unsigned short*)alloc((size_t)HID * IN_DIM * 2);
  unsigned short* g1WT  = (unsigned short*)alloc((size_t)XSTR * HID * 2);  // [Wl;Wr]^T
  unsigned short* g2WT  = (unsigned short*)alloc((size_t)XSTR * HID * 2);
  unsigned short* Ws1T  = (unsigned short*)alloc((size_t)512 * HID * 2);
  unsigned short* Ws2T  = (unsigned short*)alloc((size_t)128 * 512 * 2);
  unsigned short* hb    = (unsigned short*)alloc((size_t)N_NODES * HID * 2);
  unsigned short* s1b   = (unsigned short*)alloc((size_t)N_NODES * 512 * 2);
  unsigned short* xe    = (unsigned short*)alloc((size_t)N_NODES * XSTR * 2); // fused xl|xr
  float* bcat1  = (float*)alloc((size_t)XSTR * 4);
  float* bcat2  = (float*)alloc((size_t)XSTR * 4);
  float* C      = (float*)alloc((size_t)N_NODES * HID * 4);
  float* logits = (float*)alloc((size_t)ET * 8 * 4);
  float* alpha  = (float*)alloc((size_t)ET * 8 * 4);
  int* srcA     = (int*)alloc((size_t)ET * 4);
  int* dstA     = (int*)alloc((size_t)ET * 4);
  int* deg      = (int*)alloc(65536);
  int* cursor   = (int*)alloc(65536);
  int* rowstart = (int*)alloc(65544);
  int* src_csr  = (int*)alloc((size_t)ET * 4);
  int* dst_csr  = (int*)alloc((size_t)ET * 4);

  // --- weight/input conversions ---
  conv_bf16_kernel<<<(N_NODES * IN_DIM / 4 + 255) / 256, 256, 0, stream>>>(x, xb, N_NODES * IN_DIM / 4);
  dim3 tb(32, 8);
  transpose_conv_kernel<<<dim3(HID / 32, IN_DIM / 32), tb, 0, stream>>>(W_in, WinT, IN_DIM, HID);
  transpose_conv_kernel<<<dim3(HID / 32, HID / 32), tb, 0, stream>>>(g1Wl, g1WT, HID, HID);
  transpose_conv_kernel<<<dim3(HID / 32, HID / 32), tb, 0, stream>>>(g1Wr, g1WT + (size_t)HID * HID, HID, HID);
  transpose_conv_kernel<<<dim3(HID / 32, HID / 32), tb, 0, stream>>>(g2Wl, g2WT, HID, HID);
  transpose_conv_kernel<<<dim3(HID / 32, HID / 32), tb, 0, stream>>>(g2Wr, g2WT + (size_t)HID * HID, HID, HID);
  transpose_conv_kernel<<<dim3(512 / 32, HID / 32), tb, 0, stream>>>(Ws1, Ws1T, HID, 512);
  transpose_conv_kernel<<<dim3(128 / 32, 512 / 32), tb, 0, stream>>>(Ws2, Ws2T, 512, 128);
  concat2_kernel<<<XSTR / 256, 256, 0, stream>>>(g1bl, g1br, bcat1, HID);
  concat2_kernel<<<XSTR / 256, 256, 0, stream>>>(g2bl, g2br, bcat2, HID);

  // --- CSR build (shared by both GAT layers) ---
  hipMemsetAsync(deg, 0, 131072, stream);  // deg + cursor (contiguous)
  build_edges_kernel<<<ET / 256, 256, 0, stream>>>(ei, srcA, dstA, deg);
  scan16k_kernel<<<1, 1024, 0, stream>>>(deg, rowstart);
  scatter_edges_kernel<<<ET / 256, 256, 0, stream>>>(srcA, dstA, rowstart, cursor, src_csr, dst_csr);

  // --- input projection + LN1 + gelu ---
  gemm_bf16_kernel<0, 0><<<(N_NODES / 256) * (HID / 128), 512, 0, stream>>>(
      xb, WinT, b_in, C, nullptr, N_NODES, HID, IN_DIM, HID / 128);
  ln_gelu_kernel<0><<<N_NODES, 256, 0, stream>>>(C, ln1g, ln1b, h, hb);

  // --- GAT layer 1 (fused xl|xr projection, N=2048) ---
  gemm_bf16_kernel<0, 2><<<(N_NODES / 256) * (XSTR / 128), 512, 0, stream>>>(
      hb, g1WT, bcat1, nullptr, xe, N_NODES, XSTR, HID, XSTR / 128);
  edge_logits_kernel<<<ET / 4, 256, 0, stream>>>(xe, g1att, src_csr, dst_csr, logits);
  alpha_kernel<<<N_NODES * 8 / 256, 256, 0, stream>>>(logits, rowstart, alpha);
  gat_aggregate_kernel<<<N_NODES, 256, 0, stream>>>(xe, alpha, src_csr, rowstart, g1bo, C);
  ln_gelu_kernel<1><<<N_NODES, 256, 0, stream>>>(C, ln2g, ln2b, h, hb);

  // --- GAT layer 2 ---
  gemm_bf16_kernel<0, 2><<<(N_NODES / 256) * (XSTR / 128), 512, 0, stream>>>(
      hb, g2WT, bcat2, nullptr, xe, N_NODES, XSTR, HID, XSTR / 128);
  edge_logits_kernel<<<ET / 4, 256, 0, stream>>>(xe, g2att, src_csr, dst_csr, logits);
  alpha_kernel<<<N_NODES * 8 / 256, 256, 0, stream>>>(logits, rowstart, alpha);
  gat_aggregate_kernel<<<N_NODES, 256, 0, stream>>>(xe, alpha, src_csr, rowstart, g2bo, C);
  ln_gelu_kernel<1><<<N_NODES, 256, 0, stream>>>(C, ln3g, ln3b, h, hb);

  // --- scorer MLP ---
  gemm_bf16_kernel<1, 2><<<(N_NODES / 256) * (512 / 128), 512, 0, stream>>>(
      hb, Ws1T, bs1, nullptr, s1b, N_NODES, 512, HID, 512 / 128);
  gemm_bf16_kernel<1, 0><<<(N_NODES / 256) * 1, 512, 0, stream>>>(
      s1b, Ws2T, bs2, C, nullptr, N_NODES, 128, 512, 1);
  score_kernel<<<N_NODES / 4, 256, 0, stream>>>(C, Ws3, bs3, scores);
}